// Round 1
// baseline (190.512 us; speedup 1.0000x reference)
//
#include <hip/hip_runtime.h>
#include <hip/hip_bf16.h>
#include <float.h>

// Problem constants
#define BATCH 8
#define CHN   64
#define HW    56
#define PIX   3136          // 56*56
#define NM    576           // 64 out-ch * 9 taps

// ---------------------------------------------------------------------------
// Stage 1: invnorm[b,p] = 1/sqrt(sum_c x[b,c,p]^2)   (fp64 for exact ordering)
// ---------------------------------------------------------------------------
__global__ __launch_bounds__(256) void norm_kernel(const float* __restrict__ x,
                                                   double* __restrict__ invn) {
    int idx = blockIdx.x * 256 + threadIdx.x;     // (b,p), 25088 total = 98*256
    int b = idx / PIX, p = idx - b * PIX;
    const float* xb = x + (size_t)b * CHN * PIX + p;
    double s = 0.0;
    #pragma unroll
    for (int c = 0; c < CHN; c++) { double v = (double)xb[c * PIX]; s += v * v; }
    invn[idx] = 1.0 / sqrt(s);
}

// ---------------------------------------------------------------------------
// Stage 2: selection. Block = (b, 2 image rows). 112 active threads (1/pixel).
// LDS-stages 16-channel chunks of a 6-row x 60-col (zero-padded) tile.
// 25 fp64 dot accumulators per thread; keys = dot * invnorm_q (fp64, exact
// ordering); 9-rank selection-sort with ascending-slot tie-break (matches
// lax.top_k stability); then sort the 9 indices ascending (matches jnp.sort).
// ---------------------------------------------------------------------------
__global__ __launch_bounds__(128) void select_kernel(const float* __restrict__ x,
                                                     const double* __restrict__ invn,
                                                     int* __restrict__ sel) {
    const int b  = blockIdx.y;
    const int r0 = blockIdx.x * 2;                // first image row of tile
    __shared__ float tile[16 * 360];              // [16 ch][6 rows][60 cols]
    const int t    = threadIdx.x;
    const int lrow = t / HW;                      // 0..1 (active threads)
    const int lcol = t - lrow * HW;
    const bool active = (t < 112);

    double acc[25];
    #pragma unroll
    for (int s = 0; s < 25; s++) acc[s] = 0.0;

    const float* xb = x + (size_t)b * CHN * PIX;
    for (int cc = 0; cc < CHN; cc += 16) {
        __syncthreads();
        // stage rows r0-2 .. r0+3, cols -2..57 (zero-padded OOB)
        for (int l = t; l < 16 * 360; l += 128) {
            int cl  = l / 360; int pix = l - cl * 360;
            int lr  = pix / 60; int col = pix - lr * 60 - 2;
            int row = r0 - 2 + lr;
            float v = 0.0f;
            if (row >= 0 && row < HW && col >= 0 && col < HW)
                v = xb[(size_t)(cc + cl) * PIX + row * HW + col];
            tile[l] = v;
        }
        __syncthreads();
        if (active) {
            #pragma unroll
            for (int cl = 0; cl < 16; cl++) {
                const float* tr = &tile[cl * 360 + (lrow + 2) * 60 + (lcol + 2)];
                double ctr = (double)tr[0];
                #pragma unroll
                for (int dr = -2; dr <= 2; dr++) {
                    #pragma unroll
                    for (int dc = -2; dc <= 2; dc++) {
                        acc[(dr + 2) * 5 + (dc + 2)] += ctr * (double)tr[dr * 60 + dc];
                    }
                }
            }
        }
    }
    if (!active) return;

    const int i = r0 + lrow, j = lcol;
    const double* inb = invn + (size_t)b * PIX;
    // keys (invalid slots -> +inf); constant-indexed after unroll
    #pragma unroll
    for (int s = 0; s < 25; s++) {
        const int dr = s / 5 - 2, dc = s % 5 - 2;
        const int qi = i + dr, qj = j + dc;
        const bool valid = (qi >= 0) && (qi < HW) && (qj >= 0) && (qj < HW);
        double kv = valid ? inb[qi * HW + qj] : 0.0;
        acc[s] = valid ? acc[s] * kv : DBL_MAX;
    }
    // 9 ranks of selection-sort; strict '<' with ascending scan = stable
    unsigned int used = 0;
    int bq[9];
    #pragma unroll
    for (int r = 0; r < 9; r++) {
        double best = DBL_MAX; int bs = 0;
        #pragma unroll
        for (int s = 0; s < 25; s++) {
            bool ok = (((used >> s) & 1u) == 0u) && (acc[s] < best);
            if (ok) { best = acc[s]; bs = s; }
        }
        used |= (1u << bs);
        bq[r] = (i + bs / 5 - 2) * HW + (j + bs % 5 - 2);
    }
    // sort 9 indices ascending (bubble network, constant indices)
    #pragma unroll
    for (int a = 0; a < 8; a++) {
        #pragma unroll
        for (int c2 = 0; c2 < 8 - a; c2++) {
            int u = bq[c2], v = bq[c2 + 1];
            bq[c2] = u < v ? u : v; bq[c2 + 1] = u < v ? v : u;
        }
    }
    int p = i * HW + j;
    int* sp = sel + ((size_t)b * PIX + p) * 9;
    #pragma unroll
    for (int k = 0; k < 9; k++) sp[k] = bq[k];
}

// ---------------------------------------------------------------------------
// Stage 3: Z[b, m=o*9+k, n] = sum_c W[o,c,k] * x[b,c,n]
// GEMM M=576 K=64 N=3136, fp32 vector. 64x64 tiles, 4x4 per thread.
// ---------------------------------------------------------------------------
__global__ __launch_bounds__(256) void zgemm_kernel(const float* __restrict__ x,
                                                    const float* __restrict__ w,
                                                    float* __restrict__ Z) {
    const int b = blockIdx.z, mt = blockIdx.y, nt = blockIdx.x;
    __shared__ float As[4096];   // [c][m] 64x64
    __shared__ float Bs[4096];   // [c][n] 64x64
    const int t  = threadIdx.x;
    const int m0 = mt * 64, n0 = nt * 64;

    for (int l = t; l < 4096; l += 256) {
        int c = l >> 6, mm = l & 63;
        int m = m0 + mm;
        As[l] = w[((m / 9) * CHN + c) * 9 + (m % 9)];
    }
    const float* xb = x + (size_t)b * CHN * PIX + n0;
    for (int l = t; l < 4096; l += 256) {
        int c = l >> 6, nn = l & 63;
        Bs[l] = xb[(size_t)c * PIX + nn];
    }
    __syncthreads();

    const int tn = t & 15, tm = t >> 4;
    float4 acc0 = {0,0,0,0}, acc1 = {0,0,0,0}, acc2 = {0,0,0,0}, acc3 = {0,0,0,0};
    const float* ap = &As[tm * 4];
    const float* bp = &Bs[tn * 4];
    #pragma unroll 8
    for (int c = 0; c < 64; c++) {
        float4 av = *(const float4*)(ap + (c << 6));
        float4 bv = *(const float4*)(bp + (c << 6));
        acc0.x += av.x*bv.x; acc0.y += av.x*bv.y; acc0.z += av.x*bv.z; acc0.w += av.x*bv.w;
        acc1.x += av.y*bv.x; acc1.y += av.y*bv.y; acc1.z += av.y*bv.z; acc1.w += av.y*bv.w;
        acc2.x += av.z*bv.x; acc2.y += av.z*bv.y; acc2.z += av.z*bv.z; acc2.w += av.z*bv.w;
        acc3.x += av.w*bv.x; acc3.y += av.w*bv.y; acc3.z += av.w*bv.z; acc3.w += av.w*bv.w;
    }
    float* zp = Z + ((size_t)b * NM + m0 + tm * 4) * PIX + n0 + tn * 4;
    *(float4*)(zp)           = acc0;
    *(float4*)(zp + PIX)     = acc1;
    *(float4*)(zp + 2 * PIX) = acc2;
    *(float4*)(zp + 3 * PIX) = acc3;
}

// ---------------------------------------------------------------------------
// Stage 4: out[b, oc+o, p] = sum_k Z[b, (oc+o)*9+k, sel[b,p,k]]
// Block = (p-chunk of 256, o-chunk of 16, b). sel staged in LDS (stride-9
// int reads are bank-conflict-free: gcd(9,32)=1).
// ---------------------------------------------------------------------------
__global__ __launch_bounds__(256) void gather_kernel(const float* __restrict__ Z,
                                                     const int* __restrict__ sel,
                                                     float* __restrict__ out) {
    const int b  = blockIdx.z;
    const int oc = blockIdx.y * 16;
    const int p0 = blockIdx.x * 256;
    __shared__ int ssel[2304];
    const int t = threadIdx.x;
    const int nvalid = (PIX - p0) < 256 ? (PIX - p0) : 256;
    for (int l = t; l < nvalid * 9; l += 256)
        ssel[l] = sel[((size_t)b * PIX + p0) * 9 + l];
    __syncthreads();
    if (t >= nvalid) return;
    const int p = p0 + t;
    int s[9];
    #pragma unroll
    for (int k = 0; k < 9; k++) s[k] = ssel[t * 9 + k];
    const float* zb = Z + ((size_t)b * NM + oc * 9) * PIX;
    float* ob = out + ((size_t)b * 64 + oc) * PIX + p;
    #pragma unroll 4
    for (int o = 0; o < 16; o++) {
        float a = 0.f;
        #pragma unroll
        for (int k = 0; k < 9; k++) a += zb[(o * 9 + k) * PIX + s[k]];
        ob[o * PIX] = a;
    }
}

// ---------------------------------------------------------------------------
// Workspace layout (total ~56.2 MB):
//   invnorm : 25088 * 8        =   200,704 B  @ offset 0
//   sel     : 25088 * 9 * 4    =   903,168 B  @ offset 200,704
//   Z       : 8*576*3136*4     = 57,802,752 B @ offset 1,103,872
// ---------------------------------------------------------------------------
extern "C" void kernel_launch(void* const* d_in, const int* in_sizes, int n_in,
                              void* d_out, int out_size, void* d_ws, size_t ws_size,
                              hipStream_t stream) {
    const float* x = (const float*)d_in[0];
    const float* w = (const float*)d_in[1];
    float* out = (float*)d_out;
    char* ws = (char*)d_ws;
    double* invn = (double*)ws;
    int*    sel  = (int*)(ws + 200704);
    float*  Z    = (float*)(ws + 1103872);

    norm_kernel<<<98, 256, 0, stream>>>(x, invn);
    select_kernel<<<dim3(28, 8), 128, 0, stream>>>(x, invn, sel);
    zgemm_kernel<<<dim3(49, 9, 8), 256, 0, stream>>>(x, w, Z);
    gather_kernel<<<dim3(13, 4, 8), 256, 0, stream>>>(Z, sel, out);
}

// Round 2
// 153.917 us; speedup vs baseline: 1.2378x; 1.2378x over previous
//
#include <hip/hip_runtime.h>
#include <hip/hip_bf16.h>
#include <float.h>

// Problem constants
#define BATCH 8
#define CHN   64
#define HW    56
#define PIX   3136          // 56*56
#define NM    576           // 64 out-ch * 9 taps

// ---------------------------------------------------------------------------
// Stage 1: invnorm[b,p] = 1/sqrt(sum_c x[b,c,p]^2)   (fp64 for exact ordering)
// ---------------------------------------------------------------------------
__global__ __launch_bounds__(256) void norm_kernel(const float* __restrict__ x,
                                                   double* __restrict__ invn) {
    int idx = blockIdx.x * 256 + threadIdx.x;     // (b,p), 25088 total = 98*256
    int b = idx / PIX, p = idx - b * PIX;
    const float* xb = x + (size_t)b * CHN * PIX + p;
    double s = 0.0;
    #pragma unroll
    for (int c = 0; c < CHN; c++) { double v = (double)xb[c * PIX]; s += v * v; }
    invn[idx] = 1.0 / sqrt(s);
}

// ---------------------------------------------------------------------------
// Stage 2: selection. Block = (b, one image row). 256 threads:
//   thread (j, g), j = pixel col (56), g = candidate group (4): g handles
//   window slots s = g*7 .. g*7+6 (g=3 has only 4 valid: 21..24).
// LDS: fp64 tile [16ch][5 rows][60 cols] (zero-padded, converted at staging)
//      + fp64 keys [56][25]. Exact fp64 ordering as before: key =
//      dot(ctr,q) * invnorm[q], invalid -> DBL_MAX; stable 9-rank select,
//      then ascending index sort. Bit-identical selection vs round-1 kernel.
// ---------------------------------------------------------------------------
__global__ __launch_bounds__(256) void select_kernel(const float* __restrict__ x,
                                                     const double* __restrict__ invn,
                                                     int* __restrict__ sel) {
    const int b = blockIdx.y;
    const int r = blockIdx.x;                     // image row
    __shared__ double tile[16 * 300];             // [ch][5 rows][60 cols]
    __shared__ double keys[56 * 25];
    const int t = threadIdx.x;
    const int g = t / 56;                         // 0..3 (t<224 active)
    const int j = t - g * 56;
    const bool active = (t < 224);

    // Precompute the 7 window offsets (in fp64 elements) + validity for group g
    int off[7]; bool sval[7];
    #pragma unroll
    for (int u = 0; u < 7; u++) {
        int s = g * 7 + u;
        bool in_range = (s < 25);
        int dr = (in_range ? s : 0) / 5 - 2;
        int dc = (in_range ? s : 0) % 5 - 2;
        off[u]  = dr * 60 + dc;
        int qi = r + dr, qj = j + dc;
        sval[u] = in_range && qi >= 0 && qi < HW && qj >= 0 && qj < HW;
    }

    double acc[7];
    #pragma unroll
    for (int u = 0; u < 7; u++) acc[u] = 0.0;

    const float* xb = x + (size_t)b * CHN * PIX;
    for (int cc = 0; cc < CHN; cc += 16) {
        __syncthreads();
        // stage 16 channels of rows r-2..r+2, cols -2..57 (zero-padded)
        for (int l = t; l < 4800; l += 256) {
            int cl = l / 300; int rem = l - cl * 300;
            int lr = rem / 60; int col = rem - lr * 60 - 2;
            int row = r - 2 + lr;
            float v = 0.0f;
            if (row >= 0 && row < HW && col >= 0 && col < HW)
                v = xb[(size_t)(cc + cl) * PIX + row * HW + col];
            tile[l] = (double)v;
        }
        __syncthreads();
        if (active) {
            #pragma unroll
            for (int cl = 0; cl < 16; cl++) {
                const double* tr = &tile[cl * 300 + 2 * 60 + (j + 2)];
                double ctr = tr[0];
                #pragma unroll
                for (int u = 0; u < 7; u++) acc[u] += ctr * tr[off[u]];
            }
        }
    }
    if (active) {
        const double* inb = invn + (size_t)b * PIX;
        #pragma unroll
        for (int u = 0; u < 7; u++) {
            int s = g * 7 + u;
            if (s < 25) {
                int dr = s / 5 - 2, dc = s % 5 - 2;
                double kv = sval[u] ? acc[u] * inb[(r + dr) * HW + (j + dc)] : DBL_MAX;
                keys[j * 25 + s] = kv;
            }
        }
    }
    __syncthreads();
    if (t >= 56) return;
    const int jj = t;
    double k2[25];
    #pragma unroll
    for (int s = 0; s < 25; s++) k2[s] = keys[jj * 25 + s];
    // 9 ranks of selection-sort; strict '<' with ascending scan = stable
    unsigned int used = 0;
    int bq[9];
    #pragma unroll
    for (int rr = 0; rr < 9; rr++) {
        double best = DBL_MAX; int bs = 0;
        #pragma unroll
        for (int s = 0; s < 25; s++) {
            bool ok = (((used >> s) & 1u) == 0u) && (k2[s] < best);
            if (ok) { best = k2[s]; bs = s; }
        }
        used |= (1u << bs);
        bq[rr] = (r + bs / 5 - 2) * HW + (jj + bs % 5 - 2);
    }
    // sort 9 indices ascending (bubble network, constant indices)
    #pragma unroll
    for (int a = 0; a < 8; a++) {
        #pragma unroll
        for (int c2 = 0; c2 < 8 - a; c2++) {
            int u = bq[c2], v = bq[c2 + 1];
            bq[c2] = u < v ? u : v; bq[c2 + 1] = u < v ? v : u;
        }
    }
    int* sp = sel + ((size_t)b * PIX + r * HW + jj) * 9;
    #pragma unroll
    for (int k = 0; k < 9; k++) sp[k] = bq[k];
}

// ---------------------------------------------------------------------------
// Stage 3: Z[b, m=o*9+k, n] = sum_c W[o,c,k] * x[b,c,n]
// GEMM M=576 K=64 N=3136, fp32 vector. 64x64 tiles, 4x4 per thread.
// ---------------------------------------------------------------------------
__global__ __launch_bounds__(256) void zgemm_kernel(const float* __restrict__ x,
                                                    const float* __restrict__ w,
                                                    float* __restrict__ Z) {
    const int b = blockIdx.z, mt = blockIdx.y, nt = blockIdx.x;
    __shared__ float As[4096];   // [c][m] 64x64
    __shared__ float Bs[4096];   // [c][n] 64x64
    const int t  = threadIdx.x;
    const int m0 = mt * 64, n0 = nt * 64;

    for (int l = t; l < 4096; l += 256) {
        int c = l >> 6, mm = l & 63;
        int m = m0 + mm;
        As[l] = w[((m / 9) * CHN + c) * 9 + (m % 9)];
    }
    const float* xb = x + (size_t)b * CHN * PIX + n0;
    for (int l = t; l < 4096; l += 256) {
        int c = l >> 6, nn = l & 63;
        Bs[l] = xb[(size_t)c * PIX + nn];
    }
    __syncthreads();

    const int tn = t & 15, tm = t >> 4;
    float4 acc0 = {0,0,0,0}, acc1 = {0,0,0,0}, acc2 = {0,0,0,0}, acc3 = {0,0,0,0};
    const float* ap = &As[tm * 4];
    const float* bp = &Bs[tn * 4];
    #pragma unroll 8
    for (int c = 0; c < 64; c++) {
        float4 av = *(const float4*)(ap + (c << 6));
        float4 bv = *(const float4*)(bp + (c << 6));
        acc0.x += av.x*bv.x; acc0.y += av.x*bv.y; acc0.z += av.x*bv.z; acc0.w += av.x*bv.w;
        acc1.x += av.y*bv.x; acc1.y += av.y*bv.y; acc1.z += av.y*bv.z; acc1.w += av.y*bv.w;
        acc2.x += av.z*bv.x; acc2.y += av.z*bv.y; acc2.z += av.z*bv.z; acc2.w += av.z*bv.w;
        acc3.x += av.w*bv.x; acc3.y += av.w*bv.y; acc3.z += av.w*bv.z; acc3.w += av.w*bv.w;
    }
    float* zp = Z + ((size_t)b * NM + m0 + tm * 4) * PIX + n0 + tn * 4;
    *(float4*)(zp)           = acc0;
    *(float4*)(zp + PIX)     = acc1;
    *(float4*)(zp + 2 * PIX) = acc2;
    *(float4*)(zp + 3 * PIX) = acc3;
}

// ---------------------------------------------------------------------------
// Stage 4: out[b, oc+o, p] = sum_k Z[b, (oc+o)*9+k, sel[b,p,k]]
// ---------------------------------------------------------------------------
__global__ __launch_bounds__(256) void gather_kernel(const float* __restrict__ Z,
                                                     const int* __restrict__ sel,
                                                     float* __restrict__ out) {
    const int b  = blockIdx.z;
    const int oc = blockIdx.y * 16;
    const int p0 = blockIdx.x * 256;
    __shared__ int ssel[2304];
    const int t = threadIdx.x;
    const int nvalid = (PIX - p0) < 256 ? (PIX - p0) : 256;
    for (int l = t; l < nvalid * 9; l += 256)
        ssel[l] = sel[((size_t)b * PIX + p0) * 9 + l];
    __syncthreads();
    if (t >= nvalid) return;
    const int p = p0 + t;
    int s[9];
    #pragma unroll
    for (int k = 0; k < 9; k++) s[k] = ssel[t * 9 + k];
    const float* zb = Z + ((size_t)b * NM + oc * 9) * PIX;
    float* ob = out + ((size_t)b * 64 + oc) * PIX + p;
    #pragma unroll 4
    for (int o = 0; o < 16; o++) {
        float a = 0.f;
        #pragma unroll
        for (int k = 0; k < 9; k++) a += zb[(o * 9 + k) * PIX + s[k]];
        ob[o * PIX] = a;
    }
}

// ---------------------------------------------------------------------------
// Workspace layout (total ~56.2 MB):
//   invnorm : 25088 * 8        =   200,704 B  @ offset 0
//   sel     : 25088 * 9 * 4    =   903,168 B  @ offset 200,704
//   Z       : 8*576*3136*4     = 57,802,752 B @ offset 1,103,872
// ---------------------------------------------------------------------------
extern "C" void kernel_launch(void* const* d_in, const int* in_sizes, int n_in,
                              void* d_out, int out_size, void* d_ws, size_t ws_size,
                              hipStream_t stream) {
    const float* x = (const float*)d_in[0];
    const float* w = (const float*)d_in[1];
    float* out = (float*)d_out;
    char* ws = (char*)d_ws;
    double* invn = (double*)ws;
    int*    sel  = (int*)(ws + 200704);
    float*  Z    = (float*)(ws + 1103872);

    norm_kernel<<<98, 256, 0, stream>>>(x, invn);
    select_kernel<<<dim3(56, 8), 256, 0, stream>>>(x, invn, sel);
    zgemm_kernel<<<dim3(49, 9, 8), 256, 0, stream>>>(x, w, Z);
    gather_kernel<<<dim3(13, 4, 8), 256, 0, stream>>>(Z, sel, out);
}

// Round 3
// 143.942 us; speedup vs baseline: 1.3235x; 1.0693x over previous
//
#include <hip/hip_runtime.h>
#include <hip/hip_bf16.h>
#include <float.h>

// Problem constants
#define BATCH 8
#define CHN   64
#define HW    56
#define PIX   3136          // 56*56
#define NM    576           // 64 out-ch * 9 taps
#define LDA   72            // padded LDS row stride (bf16 elems): 144 B, 16-B aligned rows

typedef __bf16 bf16x8 __attribute__((ext_vector_type(8)));
typedef float  f32x4  __attribute__((ext_vector_type(4)));

static __device__ __forceinline__ unsigned short f2bf(float f) {
    unsigned int u = __float_as_uint(f);
    u += 0x7fffu + ((u >> 16) & 1u);          // round-to-nearest-even
    return (unsigned short)(u >> 16);
}
static __device__ __forceinline__ float bf2f(unsigned short h) {
    return __uint_as_float(((unsigned int)h) << 16);
}

// ---------------------------------------------------------------------------
// Stage 1: invnorm[b,p] = 1/sqrt(sum_c x^2) (fp64, exact ordering)
//          + fused x -> bf16 conversion (xbf[b][c][p])
// ---------------------------------------------------------------------------
__global__ __launch_bounds__(256) void norm_kernel(const float* __restrict__ x,
                                                   double* __restrict__ invn,
                                                   unsigned short* __restrict__ xbf) {
    int idx = blockIdx.x * 256 + threadIdx.x;     // (b,p), 25088 total = 98*256
    int b = idx / PIX, p = idx - b * PIX;
    const float* xb = x + (size_t)b * CHN * PIX + p;
    unsigned short* xo = xbf + (size_t)b * CHN * PIX + p;
    double s = 0.0;
    #pragma unroll
    for (int c = 0; c < CHN; c++) {
        float v = xb[c * PIX];
        s += (double)v * (double)v;
        xo[c * PIX] = f2bf(v);
    }
    invn[idx] = 1.0 / sqrt(s);
}

// ---------------------------------------------------------------------------
// Stage 2: selection (unchanged from round 2 — exact fp64 ordering).
// ---------------------------------------------------------------------------
__global__ __launch_bounds__(256) void select_kernel(const float* __restrict__ x,
                                                     const double* __restrict__ invn,
                                                     int* __restrict__ sel) {
    const int b = blockIdx.y;
    const int r = blockIdx.x;                     // image row
    __shared__ double tile[16 * 300];             // [ch][5 rows][60 cols]
    __shared__ double keys[56 * 25];
    const int t = threadIdx.x;
    const int g = t / 56;                         // 0..3 (t<224 active)
    const int j = t - g * 56;
    const bool active = (t < 224);

    int off[7]; bool sval[7];
    #pragma unroll
    for (int u = 0; u < 7; u++) {
        int s = g * 7 + u;
        bool in_range = (s < 25);
        int dr = (in_range ? s : 0) / 5 - 2;
        int dc = (in_range ? s : 0) % 5 - 2;
        off[u]  = dr * 60 + dc;
        int qi = r + dr, qj = j + dc;
        sval[u] = in_range && qi >= 0 && qi < HW && qj >= 0 && qj < HW;
    }

    double acc[7];
    #pragma unroll
    for (int u = 0; u < 7; u++) acc[u] = 0.0;

    const float* xb = x + (size_t)b * CHN * PIX;
    for (int cc = 0; cc < CHN; cc += 16) {
        __syncthreads();
        for (int l = t; l < 4800; l += 256) {
            int cl = l / 300; int rem = l - cl * 300;
            int lr = rem / 60; int col = rem - lr * 60 - 2;
            int row = r - 2 + lr;
            float v = 0.0f;
            if (row >= 0 && row < HW && col >= 0 && col < HW)
                v = xb[(size_t)(cc + cl) * PIX + row * HW + col];
            tile[l] = (double)v;
        }
        __syncthreads();
        if (active) {
            #pragma unroll
            for (int cl = 0; cl < 16; cl++) {
                const double* tr = &tile[cl * 300 + 2 * 60 + (j + 2)];
                double ctr = tr[0];
                #pragma unroll
                for (int u = 0; u < 7; u++) acc[u] += ctr * tr[off[u]];
            }
        }
    }
    if (active) {
        const double* inb = invn + (size_t)b * PIX;
        #pragma unroll
        for (int u = 0; u < 7; u++) {
            int s = g * 7 + u;
            if (s < 25) {
                int dr = s / 5 - 2, dc = s % 5 - 2;
                double kv = sval[u] ? acc[u] * inb[(r + dr) * HW + (j + dc)] : DBL_MAX;
                keys[j * 25 + s] = kv;
            }
        }
    }
    __syncthreads();
    if (t >= 56) return;
    const int jj = t;
    double k2[25];
    #pragma unroll
    for (int s = 0; s < 25; s++) k2[s] = keys[jj * 25 + s];
    unsigned int used = 0;
    int bq[9];
    #pragma unroll
    for (int rr = 0; rr < 9; rr++) {
        double best = DBL_MAX; int bs = 0;
        #pragma unroll
        for (int s = 0; s < 25; s++) {
            bool ok = (((used >> s) & 1u) == 0u) && (k2[s] < best);
            if (ok) { best = k2[s]; bs = s; }
        }
        used |= (1u << bs);
        bq[rr] = (r + bs / 5 - 2) * HW + (jj + bs % 5 - 2);
    }
    #pragma unroll
    for (int a = 0; a < 8; a++) {
        #pragma unroll
        for (int c2 = 0; c2 < 8 - a; c2++) {
            int u = bq[c2], v = bq[c2 + 1];
            bq[c2] = u < v ? u : v; bq[c2 + 1] = u < v ? v : u;
        }
    }
    int* sp = sel + ((size_t)b * PIX + r * HW + jj) * 9;
    #pragma unroll
    for (int k = 0; k < 9; k++) sp[k] = bq[k];
}

// ---------------------------------------------------------------------------
// Stage 3: Z[b, m=o*9+k, n] = sum_c W[o,c,k] * x[b,c,n]   -- bf16 MFMA.
// Block = (b, mt, nt): 64(m) x 64(n), K=64 in one shot (2 MFMA k-halves).
// LDS: As[m][c], Bs[n][c], both padded to LDA=72 (b128 frag reads, 2-way
// max bank aliasing on staging writes). Wave wv owns m-strip wv*16.
// Z stored bf16 (halves zgemm write + gather read traffic).
// ---------------------------------------------------------------------------
__global__ __launch_bounds__(256) void zgemm_kernel(const unsigned short* __restrict__ xbf,
                                                    const float* __restrict__ w,
                                                    unsigned short* __restrict__ Z) {
    const int b = blockIdx.z, mt = blockIdx.y, nt = blockIdx.x;
    __shared__ unsigned short As[64 * LDA];
    __shared__ unsigned short Bs[64 * LDA];
    const int t = threadIdx.x;
    const int m0 = mt * 64, n0 = nt * 64;

    // Stage A: As[mm][c] = bf16(W[o][c][k]), m0+mm = o*9+k  (w is L2-resident)
    #pragma unroll
    for (int it = 0; it < 16; it++) {
        int l = t + it * 256;
        int mm = l >> 6, c = l & 63;
        int m = m0 + mm;
        As[mm * LDA + c] = f2bf(w[((m / 9) * CHN + c) * 9 + (m % 9)]);
    }
    // Stage B (transpose): Bs[nn][c] = xbf[c][n0+nn]; nn = (t&7) + 8*i so
    // each write instruction spreads nn*4 + c/2 over all 32 banks (2-way max).
    {
        const unsigned short* xb = xbf + (size_t)b * CHN * PIX + n0;
        int c  = t >> 3;          // 0..31
        int nb = t & 7;
        #pragma unroll
        for (int half = 0; half < 2; half++) {
            int cc = c + half * 32;
            const unsigned short* xr = xb + (size_t)cc * PIX;
            #pragma unroll
            for (int i = 0; i < 8; i++) {
                int nn = nb + i * 8;
                Bs[nn * LDA + cc] = xr[nn];
            }
        }
    }
    __syncthreads();

    const int wv  = t >> 6;       // wave id -> m-strip
    const int ln  = t & 63;
    const int row = ln & 15;      // m (A) / n (B) index within 16-tile
    const int kq  = ln >> 4;      // quad -> k group

    const unsigned short* Abase = &As[(wv * 16 + row) * LDA];
    bf16x8 a0 = *(const bf16x8*)(Abase + kq * 8);        // k = 0..31
    bf16x8 a1 = *(const bf16x8*)(Abase + 32 + kq * 8);   // k = 32..63

    f32x4 acc[4] = {{0,0,0,0},{0,0,0,0},{0,0,0,0},{0,0,0,0}};
    #pragma unroll
    for (int ntile = 0; ntile < 4; ntile++) {
        const unsigned short* Bbase = &Bs[(ntile * 16 + row) * LDA];
        bf16x8 b0 = *(const bf16x8*)(Bbase + kq * 8);
        bf16x8 b1 = *(const bf16x8*)(Bbase + 32 + kq * 8);
        acc[ntile] = __builtin_amdgcn_mfma_f32_16x16x32_bf16(a0, b0, acc[ntile], 0, 0, 0);
        acc[ntile] = __builtin_amdgcn_mfma_f32_16x16x32_bf16(a1, b1, acc[ntile], 0, 0, 0);
    }
    // C/D layout: col = lane&15 (n), row = quad*4 + reg (m)
    unsigned short* zp = Z + ((size_t)b * NM + m0 + wv * 16) * PIX + n0;
    #pragma unroll
    for (int ntile = 0; ntile < 4; ntile++) {
        #pragma unroll
        for (int rg = 0; rg < 4; rg++) {
            zp[(size_t)(kq * 4 + rg) * PIX + ntile * 16 + row] = f2bf(acc[ntile][rg]);
        }
    }
}

// ---------------------------------------------------------------------------
// Stage 4: out[b, oc+o, p] = sum_k bf2f(Z[b, (oc+o)*9+k, sel[b,p,k]])
// ---------------------------------------------------------------------------
__global__ __launch_bounds__(256) void gather_kernel(const unsigned short* __restrict__ Z,
                                                     const int* __restrict__ sel,
                                                     float* __restrict__ out) {
    const int b  = blockIdx.z;
    const int oc = blockIdx.y * 16;
    const int p0 = blockIdx.x * 256;
    __shared__ int ssel[2304];
    const int t = threadIdx.x;
    const int nvalid = (PIX - p0) < 256 ? (PIX - p0) : 256;
    for (int l = t; l < nvalid * 9; l += 256)
        ssel[l] = sel[((size_t)b * PIX + p0) * 9 + l];
    __syncthreads();
    if (t >= nvalid) return;
    int s[9];
    #pragma unroll
    for (int k = 0; k < 9; k++) s[k] = ssel[t * 9 + k];
    const unsigned short* zb = Z + ((size_t)b * NM + oc * 9) * PIX;
    float* ob = out + ((size_t)b * 64 + oc) * PIX + p0 + t;
    #pragma unroll 4
    for (int o = 0; o < 16; o++) {
        float a = 0.f;
        #pragma unroll
        for (int k = 0; k < 9; k++) a += bf2f(zb[(o * 9 + k) * PIX + s[k]]);
        ob[o * PIX] = a;
    }
}

// ---------------------------------------------------------------------------
// Workspace layout (total ~42.9 MB):
//   invn : 25088 * 8          =    200,704 B @ 0
//   sel  : 25088 * 9 * 4      =    903,168 B @ 200,704
//   Z    : 8*576*3136 * 2     = 28,901,376 B @ 1,103,872
//   xbf  : 8*64*3136 * 2      =  3,211,264 B @ 30,005,248
// ---------------------------------------------------------------------------
extern "C" void kernel_launch(void* const* d_in, const int* in_sizes, int n_in,
                              void* d_out, int out_size, void* d_ws, size_t ws_size,
                              hipStream_t stream) {
    const float* x = (const float*)d_in[0];
    const float* w = (const float*)d_in[1];
    float* out = (float*)d_out;
    char* ws = (char*)d_ws;
    double*         invn = (double*)ws;
    int*            sel  = (int*)(ws + 200704);
    unsigned short* Z    = (unsigned short*)(ws + 1103872);
    unsigned short* xbf  = (unsigned short*)(ws + 30005248);

    norm_kernel<<<98, 256, 0, stream>>>(x, invn, xbf);
    select_kernel<<<dim3(56, 8), 256, 0, stream>>>(x, invn, sel);
    zgemm_kernel<<<dim3(49, 9, 8), 256, 0, stream>>>(xbf, w, Z);
    gather_kernel<<<dim3(13, 4, 8), 256, 0, stream>>>(Z, sel, out);
}

// Round 5
// 119.448 us; speedup vs baseline: 1.5949x; 1.2051x over previous
//
#include <hip/hip_runtime.h>
#include <hip/hip_bf16.h>
#include <float.h>

// Problem constants
#define BATCH 8
#define CHN   64
#define HW    56
#define PIX   3136          // 56*56
#define LDB   72            // band LDS stride in bf16 elems (144 B, 16-B aligned)

typedef __bf16 bf16x8 __attribute__((ext_vector_type(8)));
typedef float  f32x4  __attribute__((ext_vector_type(4)));

static __device__ __forceinline__ unsigned short f2bf(float f) {
    unsigned int u = __float_as_uint(f);
    u += 0x7fffu + ((u >> 16) & 1u);          // round-to-nearest-even
    return (unsigned short)(u >> 16);
}

// ---------------------------------------------------------------------------
// Stage 1: invnorm[b,p] = 1/sqrt(sum_c x^2) (fp64, exact ordering)
//          + fused x -> bf16 transpose: xT[b][p][c] (channel-contiguous)
// ---------------------------------------------------------------------------
__global__ __launch_bounds__(256) void norm_kernel(const float* __restrict__ x,
                                                   double* __restrict__ invn,
                                                   unsigned short* __restrict__ xT) {
    int idx = blockIdx.x * 256 + threadIdx.x;     // (b,p), 25088 total = 98*256
    int b = idx / PIX, p = idx - b * PIX;
    const float* xb = x + (size_t)b * CHN * PIX + p;
    double s = 0.0;
    unsigned int pack[32];
    #pragma unroll
    for (int c2 = 0; c2 < 32; c2++) {
        float v0 = xb[(2 * c2) * PIX];
        float v1 = xb[(2 * c2 + 1) * PIX];
        s += (double)v0 * (double)v0 + (double)v1 * (double)v1;
        pack[c2] = (unsigned int)f2bf(v0) | ((unsigned int)f2bf(v1) << 16);
    }
    uint4* dst = (uint4*)(xT + (size_t)idx * CHN);
    #pragma unroll
    for (int i = 0; i < 8; i++) dst[i] = ((uint4*)pack)[i];
    invn[idx] = 1.0 / sqrt(s);
}

// ---------------------------------------------------------------------------
// Stage 2: selection (unchanged — exact fp64 ordering, verified absmax 0.031)
// ---------------------------------------------------------------------------
__global__ __launch_bounds__(256) void select_kernel(const float* __restrict__ x,
                                                     const double* __restrict__ invn,
                                                     int* __restrict__ sel) {
    const int b = blockIdx.y;
    const int r = blockIdx.x;                     // image row
    __shared__ double tile[16 * 300];             // [ch][5 rows][60 cols]
    __shared__ double keys[56 * 25];
    const int t = threadIdx.x;
    const int g = t / 56;                         // 0..3 (t<224 active)
    const int j = t - g * 56;
    const bool active = (t < 224);

    int off[7]; bool sval[7];
    #pragma unroll
    for (int u = 0; u < 7; u++) {
        int s = g * 7 + u;
        bool in_range = (s < 25);
        int dr = (in_range ? s : 0) / 5 - 2;
        int dc = (in_range ? s : 0) % 5 - 2;
        off[u]  = dr * 60 + dc;
        int qi = r + dr, qj = j + dc;
        sval[u] = in_range && qi >= 0 && qi < HW && qj >= 0 && qj < HW;
    }

    double acc[7];
    #pragma unroll
    for (int u = 0; u < 7; u++) acc[u] = 0.0;

    const float* xb = x + (size_t)b * CHN * PIX;
    for (int cc = 0; cc < CHN; cc += 16) {
        __syncthreads();
        for (int l = t; l < 4800; l += 256) {
            int cl = l / 300; int rem = l - cl * 300;
            int lr = rem / 60; int col = rem - lr * 60 - 2;
            int row = r - 2 + lr;
            float v = 0.0f;
            if (row >= 0 && row < HW && col >= 0 && col < HW)
                v = xb[(size_t)(cc + cl) * PIX + row * HW + col];
            tile[l] = (double)v;
        }
        __syncthreads();
        if (active) {
            #pragma unroll
            for (int cl = 0; cl < 16; cl++) {
                const double* tr = &tile[cl * 300 + 2 * 60 + (j + 2)];
                double ctr = tr[0];
                #pragma unroll
                for (int u = 0; u < 7; u++) acc[u] += ctr * tr[off[u]];
            }
        }
    }
    if (active) {
        const double* inb = invn + (size_t)b * PIX;
        #pragma unroll
        for (int u = 0; u < 7; u++) {
            int s = g * 7 + u;
            if (s < 25) {
                int dr = s / 5 - 2, dc = s % 5 - 2;
                double kv = sval[u] ? acc[u] * inb[(r + dr) * HW + (j + dc)] : DBL_MAX;
                keys[j * 25 + s] = kv;
            }
        }
    }
    __syncthreads();
    if (t >= 56) return;
    const int jj = t;
    double k2[25];
    #pragma unroll
    for (int s = 0; s < 25; s++) k2[s] = keys[jj * 25 + s];
    unsigned int used = 0;
    int bq[9];
    #pragma unroll
    for (int rr = 0; rr < 9; rr++) {
        double best = DBL_MAX; int bs = 0;
        #pragma unroll
        for (int s = 0; s < 25; s++) {
            bool ok = (((used >> s) & 1u) == 0u) && (k2[s] < best);
            if (ok) { best = k2[s]; bs = s; }
        }
        used |= (1u << bs);
        bq[rr] = (r + bs / 5 - 2) * HW + (jj + bs % 5 - 2);
    }
    #pragma unroll
    for (int a = 0; a < 8; a++) {
        #pragma unroll
        for (int c2 = 0; c2 < 8 - a; c2++) {
            int u = bq[c2], v = bq[c2 + 1];
            bq[c2] = u < v ? u : v; bq[c2 + 1] = u < v ? v : u;
        }
    }
    int* sp = sel + ((size_t)b * PIX + r * HW + jj) * 9;
    #pragma unroll
    for (int k = 0; k < 9; k++) sp[k] = bq[k];
}

// ---------------------------------------------------------------------------
// Stage 3 (fused GEMM+gather): out[b,o,p] = sum_{tap,c} W[o,c,tap]*x[b,c,sel_tap(p)]
// Block = (b, image row r). LDS band[local = lr*60+col+2][c] (bf16, stride 72)
// holds rows r-2..r+2 zero-padded; qtab[tap][p] = band elem offset of
// sel_tap(p). B fragment = indexed ds_read_b128 (per-lane gather, 2-way max
// bank alias). W fragments live in registers (18 bf16x8/lane, L2-hot loads).
// Wave wv computes o-strip wv*16; acc over 9 taps x 2 k-halves.
// ---------------------------------------------------------------------------
__global__ __launch_bounds__(256) void fused_kernel(const unsigned short* __restrict__ xT,
                                                    const float* __restrict__ w,
                                                    const int* __restrict__ sel,
                                                    float* __restrict__ out) {
    const int b = blockIdx.y;
    const int r = blockIdx.x;
    __shared__ unsigned short band[300 * LDB];
    __shared__ int qtab[9 * 64];
    const int t = threadIdx.x;

    // Stage band: 300 locals x 64 ch = 2400 uint4 chunks, b128 both sides
    for (int l = t; l < 2400; l += 256) {
        int local = l >> 3, ch8 = l & 7;
        int lr = local / 60, col = local - lr * 60 - 2;
        int row = r - 2 + lr;
        uint4 v = {0, 0, 0, 0};
        if (row >= 0 && row < HW && col >= 0 && col < HW)
            v = *(const uint4*)(xT + ((size_t)b * PIX + row * HW + col) * CHN + ch8 * 8);
        *(uint4*)(&band[local * LDB + ch8 * 8]) = v;
    }
    // qtab[tap*64 + p] = premultiplied band elem offset.
    // NOTE: strided loop — 576 entries, 256 threads (R4 bug: `if (t<576)`
    // left taps 4..8 uninitialized).
    for (int l = t; l < 576; l += 256) {
        int tap = l >> 6, p = l & 63;
        int v = 0;
        if (p < HW) {
            int q  = sel[((size_t)b * PIX + r * HW + p) * 9 + tap];
            int qi = q / HW;
            int qj = q - qi * HW;
            v = ((qi - r + 2) * 60 + qj + 2) * LDB;
        }
        qtab[l] = v;
    }

    // W fragments (registers): afr[tap][half], c = half*32 + kq*8 + j
    const int wv = t >> 6, ln = t & 63;
    const int row = ln & 15, kq = ln >> 4;
    const int o = wv * 16 + row;
    bf16x8 afr[9][2];
    #pragma unroll
    for (int tap = 0; tap < 9; tap++) {
        #pragma unroll
        for (int half = 0; half < 2; half++) {
            bf16x8 a;
            #pragma unroll
            for (int j = 0; j < 8; j++) {
                int c = half * 32 + kq * 8 + j;
                a[j] = (__bf16)__uint_as_float(((unsigned int)f2bf(w[((size_t)o * CHN + c) * 9 + tap])) << 16);
            }
            afr[tap][half] = a;
        }
    }
    __syncthreads();

    f32x4 acc[4] = {{0,0,0,0},{0,0,0,0},{0,0,0,0},{0,0,0,0}};
    #pragma unroll
    for (int tap = 0; tap < 9; tap++) {
        #pragma unroll
        for (int nt = 0; nt < 4; nt++) {
            int q = qtab[tap * 64 + nt * 16 + row];
            const unsigned short* bp = &band[q + kq * 8];
            bf16x8 b0 = *(const bf16x8*)bp;
            bf16x8 b1 = *(const bf16x8*)(bp + 32);
            acc[nt] = __builtin_amdgcn_mfma_f32_16x16x32_bf16(afr[tap][0], b0, acc[nt], 0, 0, 0);
            acc[nt] = __builtin_amdgcn_mfma_f32_16x16x32_bf16(afr[tap][1], b1, acc[nt], 0, 0, 0);
        }
    }
    // C/D: col = lane&15 = p-within-tile, row = kq*4+rg = o-within-strip
    float* ob = out + ((size_t)b * 64 + wv * 16 + kq * 4) * PIX + r * HW;
    #pragma unroll
    for (int nt = 0; nt < 4; nt++) {
        int p = nt * 16 + row;
        if (p < HW) {
            #pragma unroll
            for (int rg = 0; rg < 4; rg++) ob[(size_t)rg * PIX + p] = acc[nt][rg];
        }
    }
}

// ---------------------------------------------------------------------------
// Workspace layout (total ~4.3 MB):
//   invn : 25088 * 8       =   200,704 B @ 0
//   sel  : 25088 * 9 * 4   =   903,168 B @ 200,704
//   xT   : 8*3136*64 * 2   = 3,211,264 B @ 1,103,872  (16-B aligned)
// ---------------------------------------------------------------------------
extern "C" void kernel_launch(void* const* d_in, const int* in_sizes, int n_in,
                              void* d_out, int out_size, void* d_ws, size_t ws_size,
                              hipStream_t stream) {
    const float* x = (const float*)d_in[0];
    const float* w = (const float*)d_in[1];
    float* out = (float*)d_out;
    char* ws = (char*)d_ws;
    double*         invn = (double*)ws;
    int*            sel  = (int*)(ws + 200704);
    unsigned short* xT   = (unsigned short*)(ws + 1103872);

    norm_kernel<<<98, 256, 0, stream>>>(x, invn, xT);
    select_kernel<<<dim3(56, 8), 256, 0, stream>>>(x, invn, sel);
    fused_kernel<<<dim3(56, 8), 256, 0, stream>>>(xT, w, sel, out);
}

// Round 6
// 115.666 us; speedup vs baseline: 1.6471x; 1.0327x over previous
//
#include <hip/hip_runtime.h>
#include <hip/hip_bf16.h>
#include <float.h>

// Problem constants
#define BATCH 8
#define CHN   64
#define HW    56
#define PIX   3136          // 56*56
#define LDB   72            // band LDS stride in bf16 elems (144 B, 16-B aligned)

typedef __bf16 bf16x8 __attribute__((ext_vector_type(8)));
typedef float  f32x4  __attribute__((ext_vector_type(4)));

static __device__ __forceinline__ unsigned short f2bf(float f) {
    unsigned int u = __float_as_uint(f);
    u += 0x7fffu + ((u >> 16) & 1u);          // round-to-nearest-even
    return (unsigned short)(u >> 16);
}

// ---------------------------------------------------------------------------
// Stage 1: invnorm[b,p] = 1/sqrt(sum_c x^2) (fp64, exact ordering)
//          + fused x -> bf16 transpose: xT[b][p][c] (channel-contiguous)
// ---------------------------------------------------------------------------
__global__ __launch_bounds__(256) void norm_kernel(const float* __restrict__ x,
                                                   double* __restrict__ invn,
                                                   unsigned short* __restrict__ xT) {
    int idx = blockIdx.x * 256 + threadIdx.x;     // (b,p), 25088 total = 98*256
    int b = idx / PIX, p = idx - b * PIX;
    const float* xb = x + (size_t)b * CHN * PIX + p;
    double s = 0.0;
    unsigned int pack[32];
    #pragma unroll
    for (int c2 = 0; c2 < 32; c2++) {
        float v0 = xb[(2 * c2) * PIX];
        float v1 = xb[(2 * c2 + 1) * PIX];
        s += (double)v0 * (double)v0 + (double)v1 * (double)v1;
        pack[c2] = (unsigned int)f2bf(v0) | ((unsigned int)f2bf(v1) << 16);
    }
    uint4* dst = (uint4*)(xT + (size_t)idx * CHN);
    #pragma unroll
    for (int i = 0; i < 8; i++) dst[i] = ((uint4*)pack)[i];
    invn[idx] = 1.0 / sqrt(s);
}

// ---------------------------------------------------------------------------
// Stage 2a: partial fp64 dots over a 32-channel half.
// Block = (r, b, half). fp32 LDS tile (19.2 KB -> ~8 blocks/CU); products
// computed as f64(ctr)*f64(val) — cvt is exact, so dot bits match a full
// fp64 pipeline. part[b][half][r][j][s] holds raw dots (zero-padded tile
// makes OOB slots 0; validity applied in select_pick).
// ---------------------------------------------------------------------------
__global__ __launch_bounds__(256) void select_part(const float* __restrict__ x,
                                                   double* __restrict__ part) {
    const int b = blockIdx.y;
    const int r = blockIdx.x;                     // image row
    const int half = blockIdx.z;                  // channel half (32 ch)
    __shared__ float tile[16 * 300];              // [ch][5 rows][60 cols]
    const int t = threadIdx.x;
    const int g = t / 56;                         // 0..3 (t<224 active)
    const int j = t - g * 56;
    const bool active = (t < 224);

    int off[7];
    #pragma unroll
    for (int u = 0; u < 7; u++) {
        int s = g * 7 + u;
        int dr = (s < 25 ? s : 0) / 5 - 2;
        int dc = (s < 25 ? s : 0) % 5 - 2;
        off[u] = dr * 60 + dc;
    }

    double acc[7];
    #pragma unroll
    for (int u = 0; u < 7; u++) acc[u] = 0.0;

    const float* xb = x + (size_t)b * CHN * PIX;
    for (int ci = 0; ci < 2; ci++) {
        const int cc = half * 32 + ci * 16;
        __syncthreads();
        for (int l = t; l < 4800; l += 256) {
            int cl = l / 300; int rem = l - cl * 300;
            int lr = rem / 60; int col = rem - lr * 60 - 2;
            int row = r - 2 + lr;
            float v = 0.0f;
            if (row >= 0 && row < HW && col >= 0 && col < HW)
                v = xb[(size_t)(cc + cl) * PIX + row * HW + col];
            tile[l] = v;
        }
        __syncthreads();
        if (active) {
            #pragma unroll
            for (int cl = 0; cl < 16; cl++) {
                const float* tr = &tile[cl * 300 + 2 * 60 + (j + 2)];
                double ctr = (double)tr[0];
                #pragma unroll
                for (int u = 0; u < 7; u++) acc[u] += ctr * (double)tr[off[u]];
            }
        }
    }
    if (!active) return;
    double* pp = part + ((size_t)(b * 2 + half) * 56 + r) * 1400 + j * 25;
    #pragma unroll
    for (int u = 0; u < 7; u++) {
        int s = g * 7 + u;
        if (s < 25) pp[s] = acc[u];
    }
}

// ---------------------------------------------------------------------------
// Stage 2b: combine halves, apply invnorm + validity, 9-of-25 stable select,
// ascending index sort. Selection logic bit-identical to verified R2 kernel
// (fp64 keys; fp64 re-association of the c-sum cannot flip an fp32-level
// comparison, and exact ties don't occur in random data).
// ---------------------------------------------------------------------------
__global__ __launch_bounds__(256) void select_pick(const double* __restrict__ part,
                                                   const double* __restrict__ invn,
                                                   int* __restrict__ sel) {
    const int b = blockIdx.y;
    const int r = blockIdx.x;
    __shared__ double keys[1400];
    const int t = threadIdx.x;
    const double* p0 = part + ((size_t)(b * 2 + 0) * 56 + r) * 1400;
    const double* p1 = part + ((size_t)(b * 2 + 1) * 56 + r) * 1400;
    for (int l = t; l < 1400; l += 256) keys[l] = p0[l] + p1[l];
    __syncthreads();
    if (t >= 56) return;
    const int jj = t;
    const double* inb = invn + (size_t)b * PIX;
    double k2[25];
    #pragma unroll
    for (int s = 0; s < 25; s++) {
        int dr = s / 5 - 2, dc = s % 5 - 2;
        int qi = r + dr, qj = jj + dc;
        bool valid = qi >= 0 && qi < HW && qj >= 0 && qj < HW;
        k2[s] = valid ? keys[jj * 25 + s] * inb[qi * HW + qj] : DBL_MAX;
    }
    unsigned int used = 0;
    int bq[9];
    #pragma unroll
    for (int rr = 0; rr < 9; rr++) {
        double best = DBL_MAX; int bs = 0;
        #pragma unroll
        for (int s = 0; s < 25; s++) {
            bool ok = (((used >> s) & 1u) == 0u) && (k2[s] < best);
            if (ok) { best = k2[s]; bs = s; }
        }
        used |= (1u << bs);
        bq[rr] = (r + bs / 5 - 2) * HW + (jj + bs % 5 - 2);
    }
    #pragma unroll
    for (int a = 0; a < 8; a++) {
        #pragma unroll
        for (int c2 = 0; c2 < 8 - a; c2++) {
            int u = bq[c2], v = bq[c2 + 1];
            bq[c2] = u < v ? u : v; bq[c2 + 1] = u < v ? v : u;
        }
    }
    int* sp = sel + ((size_t)b * PIX + r * HW + jj) * 9;
    #pragma unroll
    for (int k = 0; k < 9; k++) sp[k] = bq[k];
}

// ---------------------------------------------------------------------------
// Stage 3 (fused GEMM+gather): out[b,o,p] = sum_{tap,c} W[o,c,tap]*x[b,c,sel_tap(p)]
// (verified R5: band in LDS, per-lane indexed ds_read_b128 B-fragments,
//  W fragments in registers, 72 MFMA/wave, direct out write)
// ---------------------------------------------------------------------------
__global__ __launch_bounds__(256) void fused_kernel(const unsigned short* __restrict__ xT,
                                                    const float* __restrict__ w,
                                                    const int* __restrict__ sel,
                                                    float* __restrict__ out) {
    const int b = blockIdx.y;
    const int r = blockIdx.x;
    __shared__ unsigned short band[300 * LDB];
    __shared__ int qtab[9 * 64];
    const int t = threadIdx.x;

    for (int l = t; l < 2400; l += 256) {
        int local = l >> 3, ch8 = l & 7;
        int lr = local / 60, col = local - lr * 60 - 2;
        int row = r - 2 + lr;
        uint4 v = {0, 0, 0, 0};
        if (row >= 0 && row < HW && col >= 0 && col < HW)
            v = *(const uint4*)(xT + ((size_t)b * PIX + row * HW + col) * CHN + ch8 * 8);
        *(uint4*)(&band[local * LDB + ch8 * 8]) = v;
    }
    for (int l = t; l < 576; l += 256) {
        int tap = l >> 6, p = l & 63;
        int v = 0;
        if (p < HW) {
            int q  = sel[((size_t)b * PIX + r * HW + p) * 9 + tap];
            int qi = q / HW;
            int qj = q - qi * HW;
            v = ((qi - r + 2) * 60 + qj + 2) * LDB;
        }
        qtab[l] = v;
    }

    const int wv = t >> 6, ln = t & 63;
    const int row = ln & 15, kq = ln >> 4;
    const int o = wv * 16 + row;
    bf16x8 afr[9][2];
    #pragma unroll
    for (int tap = 0; tap < 9; tap++) {
        #pragma unroll
        for (int half = 0; half < 2; half++) {
            bf16x8 a;
            #pragma unroll
            for (int j = 0; j < 8; j++) {
                int c = half * 32 + kq * 8 + j;
                a[j] = (__bf16)__uint_as_float(((unsigned int)f2bf(w[((size_t)o * CHN + c) * 9 + tap])) << 16);
            }
            afr[tap][half] = a;
        }
    }
    __syncthreads();

    f32x4 acc[4] = {{0,0,0,0},{0,0,0,0},{0,0,0,0},{0,0,0,0}};
    #pragma unroll
    for (int tap = 0; tap < 9; tap++) {
        #pragma unroll
        for (int nt = 0; nt < 4; nt++) {
            int q = qtab[tap * 64 + nt * 16 + row];
            const unsigned short* bp = &band[q + kq * 8];
            bf16x8 b0 = *(const bf16x8*)bp;
            bf16x8 b1 = *(const bf16x8*)(bp + 32);
            acc[nt] = __builtin_amdgcn_mfma_f32_16x16x32_bf16(afr[tap][0], b0, acc[nt], 0, 0, 0);
            acc[nt] = __builtin_amdgcn_mfma_f32_16x16x32_bf16(afr[tap][1], b1, acc[nt], 0, 0, 0);
        }
    }
    float* ob = out + ((size_t)b * 64 + wv * 16 + kq * 4) * PIX + r * HW;
    #pragma unroll
    for (int nt = 0; nt < 4; nt++) {
        int p = nt * 16 + row;
        if (p < HW) {
            #pragma unroll
            for (int rg = 0; rg < 4; rg++) ob[(size_t)rg * PIX + p] = acc[nt][rg];
        }
    }
}

// ---------------------------------------------------------------------------
// Workspace layout (total ~14.4 MB):
//   invn : 25088 * 8         =    200,704 B @ 0
//   sel  : 25088 * 9 * 4     =    903,168 B @ 200,704
//   xT   : 8*3136*64 * 2     =  3,211,264 B @ 1,103,872
//   part : 8*2*56*1400 * 8   = 10,035,200 B @ 4,315,136
// ---------------------------------------------------------------------------
extern "C" void kernel_launch(void* const* d_in, const int* in_sizes, int n_in,
                              void* d_out, int out_size, void* d_ws, size_t ws_size,
                              hipStream_t stream) {
    const float* x = (const float*)d_in[0];
    const float* w = (const float*)d_in[1];
    float* out = (float*)d_out;
    char* ws = (char*)d_ws;
    double*         invn = (double*)ws;
    int*            sel  = (int*)(ws + 200704);
    unsigned short* xT   = (unsigned short*)(ws + 1103872);
    double*         part = (double*)(ws + 4315136);

    norm_kernel<<<98, 256, 0, stream>>>(x, invn, xT);
    select_part<<<dim3(56, 8, 2), 256, 0, stream>>>(x, part);
    select_pick<<<dim3(56, 8), 256, 0, stream>>>(part, invn, sel);
    fused_kernel<<<dim3(56, 8), 256, 0, stream>>>(xT, w, sel, out);
}